// Round 12
// baseline (650.664 us; speedup 1.0000x reference)
//
#include <hip/hip_runtime.h>
#include <stdint.h>

typedef unsigned int u32;
typedef unsigned short u16;
typedef unsigned char u8;
typedef unsigned long long u64;
typedef _Float16 h2 __attribute__((ext_vector_type(2)));
typedef _Float16 h4 __attribute__((ext_vector_type(4)));
typedef _Float16 h8 __attribute__((ext_vector_type(8)));
typedef float f4 __attribute__((ext_vector_type(4)));

#define DEV __device__ __forceinline__

constexpr int HWp = 9216;   // 96*96

// ---------- workspace layout (bytes) ----------
constexpr size_t O_I16 = 0;                          // f16 [b][9216][48]: th 0-15, ph 16-31, g 32-47
constexpr size_t N_I16 = 2ull * 9216 * 48;           // halves
constexpr size_t O_Z   = O_I16 + N_I16 * 2;          // f32 [b][576][49][16] per-query z (normalized)
constexpr size_t N_Z   = 2ull * 576 * 784;
constexpr size_t WS_NEED = O_Z + N_Z * 4;            // ~5.38 MB

DEV float bf2f(u16 x) { return __uint_as_float(((u32)x) << 16); }
DEV int clampi(int v, int lo, int hi) { return v < lo ? lo : (v > hi ? hi : v); }
DEV float cvt(const void* p, int i, bool f32) {
  return f32 ? ((const float*)p)[i] : bf2f(((const u16*)p)[i]);
}
DEV float dot2(h2 a, h2 b, float c) {
#if __has_builtin(__builtin_amdgcn_fdot2)
  return __builtin_amdgcn_fdot2(a, b, c, false);
#else
  return c + (float)a[0]*(float)b[0] + (float)a[1]*(float)b[1];
#endif
}
DEV float dot8(h8 a, h8 b, float c) {
  c = dot2(__builtin_shufflevector(a,a,0,1), __builtin_shufflevector(b,b,0,1), c);
  c = dot2(__builtin_shufflevector(a,a,2,3), __builtin_shufflevector(b,b,2,3), c);
  c = dot2(__builtin_shufflevector(a,a,4,5), __builtin_shufflevector(b,b,4,5), c);
  c = dot2(__builtin_shufflevector(a,a,6,7), __builtin_shufflevector(b,b,6,7), c);
  return c;
}
// per-block dtype detect: sample first 256 u16 of array; f32 data -> ~28 hits, bf16 -> 0.
DEV bool hit256(const void* p, int tid) {
  u16 v = ((const u16*)p)[tid];
  return (((u32)v >> 7) & 0xFFu) >= 0xC8u;
}

// ---------- K1: conv1x1 -> channel-last f16 image [b][px][48]; self-sufficient ----------
__global__ __launch_bounds__(256, 2) void k1_conv(const void* vid, const void* wth, const void* bth,
    const void* wph, const void* bph, const void* wg, const void* bg, u8* ws)
{
  __shared__ float vidL[64 * 65];        // [px][c] pad 65
  __shared__ float wL[48 * 65];          // [o][c] pad 65
  __shared__ float bL[48];
  __shared__ __align__(16) _Float16 outL[64 * 48];
  __shared__ int redL[8];
  int tid = threadIdx.x;
  int g0 = blockIdx.x * 64;
  int b = g0 / HWp, px0 = g0 % HWp;

  {
    u64 b1 = __ballot(hit256(vid, tid));
    u64 b2 = __ballot(hit256(wth, tid));
    if ((tid & 63) == 0) { redL[tid >> 6] = __popcll(b1); redL[4 + (tid >> 6)] = __popcll(b2); }
  }
  __syncthreads();
  const bool vf = (redL[0] + redL[1] + redL[2] + redL[3]) >= 4;
  const bool wf = (redL[4] + redL[5] + redL[6] + redL[7]) >= 4;

  if (wf) {  // vectorized weight staging: 3 f4 loads/thread
    for (int e = tid; e < 768; e += 256) {
      int a = e >> 8, j = e & 255;
      int o = j >> 4, c4 = (j & 15) << 2;
      const float* src = (a == 0) ? (const float*)wth : (a == 1) ? (const float*)wph : (const float*)wg;
      f4 x = *(const f4*)(src + o*64 + c4);
#pragma unroll
      for (int jj = 0; jj < 4; ++jj) wL[(a*16 + o)*65 + c4 + jj] = x[jj];
    }
  } else {
    for (int e = tid; e < 384; e += 256) {
      int a = e >> 7, j = e & 127;
      int o = j >> 5, c2 = (j & 31) << 1;
      const u16* src = (a == 0) ? (const u16*)wth : (a == 1) ? (const u16*)wph : (const u16*)wg;
      u32 x = *(const u32*)(src + o*64 + c2);
      wL[(a*16 + o)*65 + c2]     = bf2f((u16)(x & 0xFFFF));
      wL[(a*16 + o)*65 + c2 + 1] = bf2f((u16)(x >> 16));
    }
  }
  if (tid < 48) bL[tid] = (tid < 16) ? cvt(bth, tid, wf) : (tid < 32) ? cvt(bph, tid-16, wf) : cvt(bg, tid-32, wf);
  if (vf) {
    const float* v = (const float*)vid;
    for (int e = tid; e < 1024; e += 256) {   // f4 loads: 16B/lane
      int c = e >> 4, qd = e & 15;
      f4 x = *(const f4*)(v + (size_t)(b*64 + c)*HWp + px0 + qd*4);
#pragma unroll
      for (int j = 0; j < 4; ++j) vidL[(qd*4 + j)*65 + c] = x[j];
    }
  } else {
    const u16* v = (const u16*)vid;
    for (int e = tid; e < 2048; e += 256) {   // u32 = 2 px
      int c = e >> 5, pp = (e & 31) * 2;
      u32 x = *(const u32*)(v + (size_t)(b*64 + c)*HWp + px0 + pp);
      vidL[pp*65 + c]     = bf2f((u16)(x & 0xFFFF));
      vidL[(pp+1)*65 + c] = bf2f((u16)(x >> 16));
    }
  }
  __syncthreads();

  int px = tid >> 2, h = tid & 3;
  float acc[12];
#pragma unroll
  for (int j = 0; j < 12; ++j) acc[j] = bL[h*12 + j];
  for (int c = 0; c < 64; ++c) {
    float v = vidL[px*65 + c];
#pragma unroll
    for (int j = 0; j < 12; ++j) acc[j] += wL[(h*12 + j)*65 + c] * v;
  }
#pragma unroll
  for (int j = 0; j < 12; ++j) outL[px*48 + h*12 + j] = (_Float16)acc[j];
  __syncthreads();

  _Float16* img = (_Float16*)(ws + O_I16);
  for (int e = tid; e < 384; e += 256) {   // coalesced h8 stores
    int p = e / 6, seg = e % 6;
    *(h8*)(img + (size_t)(b*HWp + px0 + p)*48 + seg*8) = *(const h8*)&outL[p*48 + seg*8];
  }
}

// ---------- K2: channel-split 2-pass attention; 16.9 KB LDS -> high residency ----------
__global__ __launch_bounds__(256, 2) void k2_attn(u8* ws)
{
  __shared__ __align__(16) _Float16 tile[729*8];           // one 8-channel plane (phi/g halves)
  __shared__ __align__(16) _Float16 thA[49*8], thB[49*8];  // theta ch0-7 / ch8-15
  __shared__ float scL[441];
  __shared__ u8 crL[441], ccL[441];
  __shared__ u16 selL[100];
  __shared__ float wgtF[104];  // unnormalized weights (wave-0 scratch)
  __shared__ u32 wgtH[100];    // normalized weight as packed h2

  const int tid = threadIdx.x, blk = blockIdx.x;
  const int b = blk / 576, q = blk % 576;
  const int qi = (q / 24) * 4, qj = (q % 24) * 4;
  const _Float16* I = (const _Float16*)(ws + O_I16) + (size_t)b * HWp * 48;

  for (int e = tid; e < 441; e += 256) {
    int d1 = e / 21, d2 = e % 21;
    crL[e] = (u8)clampi(qi + d1 - 10, 0, 95);
    ccL[e] = (u8)clampi(qj + d2 - 10, 0, 95);
  }
  for (int e = tid; e < 98; e += 256) {   // theta patch (both halves)
    int p = e >> 1, hf = e & 1, di = p / 7, dj = p % 7;
    int ty = clampi(qi + di - 3, 0, 95), tx = clampi(qj + dj - 3, 0, 95);
    *(h8*)&(hf ? thB : thA)[p*8] = *(const h8*)(I + (size_t)(ty*96 + tx)*48 + hf*8);
  }
  for (int e = tid; e < 729; e += 256) {  // phi half 0 (image ch 16-23)
    int row = e / 27, col = e % 27;
    int gy = clampi(qi - 13 + row, 0, 95), gx = clampi(qj - 13 + col, 0, 95);
    *(h8*)&tile[e*8] = *(const h8*)(I + (size_t)(gy*96 + gx)*48 + 16);
  }
  __syncthreads();

  // ---- paired-candidate window setup (registers live across passes) ----
  const bool active = tid < 231;
  int uu = active ? tid : 0;
  int row = uu / 11, m = uu % 11;
  const bool has1 = active && (m < 10);
  int d2_0 = (m < 10) ? 2*m : 20;
  const int c0 = row*21 + d2_0;
  int cc0 = clampi(qj + d2_0 - 10, 0, 95);
  const int s = clampi(qj + d2_0 - 9, 0, 95) - cc0;   // 0 or 1
  int cr0 = clampi(qi + row - 10, 0, 95);
  int ro[7], tw[8];
#pragma unroll
  for (int i = 0; i < 7; ++i) ro[i] = (clampi(cr0 + i - 3, 0, 95) - qi + 13) * 216;  // *27*8
#pragma unroll
  for (int j = 0; j < 8; ++j) {
    int t = clampi(cc0 + j - 3, 0, 95) - (qj - 13);
    tw[j] = (t > 26 ? 26 : t) * 8;
  }

  { // score pass 0: channels 0-7 (thA)
    float a0 = 0.f, a1 = 0.f;
    for (int di = 0; di < 7; ++di) {
      int r = ro[di];
#pragma unroll
      for (int j = 0; j < 8; ++j) {
        h8 hv = *(const h8*)&tile[r + tw[j]];
        if (j < 7) a0 = dot8(*(const h8*)&thA[(di*7 + j)*8], hv, a0);
        int dj1 = j - s;
        bool v1 = has1 && (dj1 >= 0) && (dj1 <= 6);
        float rr = dot8(*(const h8*)&thA[(di*7 + clampi(dj1, 0, 6))*8], hv, a1);
        a1 = v1 ? rr : a1;
      }
    }
    if (active) scL[c0] = a0;
    if (has1) scL[c0 + 1] = a1;
  }
  __syncthreads();

  for (int e = tid; e < 729; e += 256) {  // phi half 1 (image ch 24-31)
    int rw = e / 27, col = e % 27;
    int gy = clampi(qi - 13 + rw, 0, 95), gx = clampi(qj - 13 + col, 0, 95);
    *(h8*)&tile[e*8] = *(const h8*)(I + (size_t)(gy*96 + gx)*48 + 24);
  }
  __syncthreads();

  { // score pass 1: channels 8-15 (thB); scL += (same final order as a0A + a0B)
    float a0 = 0.f, a1 = 0.f;
    for (int di = 0; di < 7; ++di) {
      int r = ro[di];
#pragma unroll
      for (int j = 0; j < 8; ++j) {
        h8 hv = *(const h8*)&tile[r + tw[j]];
        if (j < 7) a0 = dot8(*(const h8*)&thB[(di*7 + j)*8], hv, a0);
        int dj1 = j - s;
        bool v1 = has1 && (dj1 >= 0) && (dj1 <= 6);
        float rr = dot8(*(const h8*)&thB[(di*7 + clampi(dj1, 0, 6))*8], hv, a1);
        a1 = v1 ? rr : a1;
      }
    }
    if (active) scL[c0] += a0;
    if (has1) scL[c0 + 1] += a1;
  }
  __syncthreads();

  if (tid >= 64) {  // waves 1-3: stage g half 0 (image ch 32-39) while wave 0 selects
    for (int e = tid - 64; e < 729; e += 192) {
      int rw = e / 27, col = e % 27;
      int gy = clampi(qi - 13 + rw, 0, 95), gx = clampi(qj - 13 + col, 0, 95);
      *(h8*)&tile[e*8] = *(const h8*)(I + (size_t)(gy*96 + gx)*48 + 32);
    }
  } else {
    // wave 0: exact top-100 via 41-round radix threshold on UNIQUE keys
    // key = (orderable_score << 9) | (511 - idx): distinct, desc order = score desc then idx asc (jax stable)
    const int lane = tid;
    const u64 lt = (1ull << lane) - 1ull;
    u64 kv[7];
#pragma unroll
    for (int sb = 0; sb < 7; ++sb) {
      int idx = sb * 64 + lane;
      if (idx < 441) {
        u32 bb = __float_as_uint(scL[idx]);
        u32 ob = (bb & 0x80000000u) ? ~bb : (bb | 0x80000000u);
        kv[sb] = ((u64)ob << 9) | (u64)(511 - idx);
      } else kv[sb] = 0ull;
    }
    u64 mx = kv[0];
#pragma unroll
    for (int sb = 1; sb < 7; ++sb) mx = (kv[sb] > mx) ? kv[sb] : mx;
    for (int off = 1; off < 64; off <<= 1) { u64 o = __shfl_xor(mx, off, 64); mx = (o > mx) ? o : mx; }
    float vmax;
    { u32 ob = (u32)(mx >> 9); u32 bb = (ob & 0x80000000u) ? (ob & 0x7FFFFFFFu) : ~ob; vmax = __uint_as_float(bb); }
    u64 T = 0;
    for (int bit = 40; bit >= 0; --bit) {
      u64 cand = T | (1ull << bit);
      int cnt = 0;
#pragma unroll
      for (int sb = 0; sb < 7; ++sb) cnt += __popcll(__ballot(kv[sb] >= cand));
      if (cnt >= 100) T = cand;
    }
    float dloc = 0.f; int base = 0;
#pragma unroll
    for (int sb = 0; sb < 7; ++sb) {
      bool incl = kv[sb] >= T;
      u64 ib = __ballot(incl);
      if (incl) {
        int idx = 511 - (int)(kv[sb] & 0x1FFull);
        u32 ob = (u32)(kv[sb] >> 9);
        u32 bb = (ob & 0x80000000u) ? (ob & 0x7FFFFFFFu) : ~ob;
        float w = __expf(10.f * (__uint_as_float(bb) - vmax));
        int pos = base + __popcll(ib & lt);
        selL[pos] = (u16)idx;
        wgtF[pos] = w;
        dloc += w;
      }
      base += __popcll(ib);
    }
    for (int off = 1; off < 64; off <<= 1) dloc += __shfl_xor(dloc, off, 64);
    float inv = 1.f / dloc;
    for (int k = lane; k < 100; k += 64) {
      _Float16 wh = (_Float16)(wgtF[k] * inv);
      h2 p2; p2[0] = wh; p2[1] = wh;
      wgtH[k] = __builtin_bit_cast(u32, p2);
    }
  }
  __syncthreads();

  // ---- z pass 0: g channels 0-7; wave w in {0,1} handles channel-quad w ----
  {
    int w = tid >> 6, p = tid & 63;
    if (w < 2 && p < 49) {
      int di = p / 7, dj = p % 7;
      h2 accA; accA[0] = (_Float16)0.f; accA[1] = (_Float16)0.f;
      h2 accB = accA;
      for (int k = 0; k < 100; ++k) {
        int si = selL[k];
        int ty = clampi((int)crL[si] + di - 3, 0, 95) - qi + 13;
        int tx = clampi((int)ccL[si] + dj - 3, 0, 95) - qj + 13;
        h4 g = *(const h4*)&tile[(ty*27 + tx)*8 + w*4];
        h2 w2 = __builtin_bit_cast(h2, wgtH[k]);
        accA += w2 * __builtin_shufflevector(g, g, 0, 1);
        accB += w2 * __builtin_shufflevector(g, g, 2, 3);
      }
      f4 zv; zv[0] = (float)accA[0]; zv[1] = (float)accA[1]; zv[2] = (float)accB[0]; zv[3] = (float)accB[1];
      *(f4*)((float*)(ws + O_Z) + (size_t)(b*576 + q)*784 + p*16 + w*4) = zv;
    }
  }
  __syncthreads();

  for (int e = tid; e < 729; e += 256) {  // g half 1 (image ch 40-47)
    int rw = e / 27, col = e % 27;
    int gy = clampi(qi - 13 + rw, 0, 95), gx = clampi(qj - 13 + col, 0, 95);
    *(h8*)&tile[e*8] = *(const h8*)(I + (size_t)(gy*96 + gx)*48 + 40);
  }
  __syncthreads();

  // ---- z pass 1: g channels 8-15 ----
  {
    int w = tid >> 6, p = tid & 63;
    if (w < 2 && p < 49) {
      int di = p / 7, dj = p % 7;
      h2 accA; accA[0] = (_Float16)0.f; accA[1] = (_Float16)0.f;
      h2 accB = accA;
      for (int k = 0; k < 100; ++k) {
        int si = selL[k];
        int ty = clampi((int)crL[si] + di - 3, 0, 95) - qi + 13;
        int tx = clampi((int)ccL[si] + dj - 3, 0, 95) - qj + 13;
        h4 g = *(const h4*)&tile[(ty*27 + tx)*8 + w*4];
        h2 w2 = __builtin_bit_cast(h2, wgtH[k]);
        accA += w2 * __builtin_shufflevector(g, g, 0, 1);
        accB += w2 * __builtin_shufflevector(g, g, 2, 3);
      }
      f4 zv; zv[0] = (float)accA[0]; zv[1] = (float)accA[1]; zv[2] = (float)accB[0]; zv[3] = (float)accB[1];
      *(f4*)((float*)(ws + O_Z) + (size_t)(b*576 + q)*784 + p*16 + 8 + w*4) = zv;
    }
  }
}

// ---------- K3: self-sufficient gather overlap-add + folded epilogue ----------
__global__ __launch_bounds__(256, 2) void k3_out(const void* vid, const void* ww, const void* bw,
    const void* wc33, const void* bc33, float* out, const u8* ws)
{
  __shared__ float znL[16 * 96];
  __shared__ float vidL[64 * 96];
  __shared__ float WvL[32 * 65];
  __shared__ float WcL[32 * 65];
  __shared__ float wwL[1024];
  __shared__ float bwL[64];
  __shared__ float W1L[32 * 17];
  __shared__ float B0L[32];
  __shared__ u8 McL[96], MQL[384], MRL[384];
  __shared__ int redL[8];
  const int tid = threadIdx.x, blk = blockIdx.x;
  const int b = blk / 192, rem = blk % 192, y = rem >> 1, oh = (rem & 1) * 32;

  {
    u64 b1 = __ballot(hit256(vid, tid));
    u64 b2 = __ballot(hit256(wc33, tid));
    if ((tid & 63) == 0) { redL[tid >> 6] = __popcll(b1); redL[4 + (tid >> 6)] = __popcll(b2); }
  }
  __syncthreads();
  const bool vf = (redL[0] + redL[1] + redL[2] + redL[3]) >= 4;
  const bool wfl = (redL[4] + redL[5] + redL[6] + redL[7]) >= 4;

  if (wfl) {   // vectorized weight staging
    const float* wc = (const float*)wc33;
    for (int e = tid; e < 1024; e += 256) {    // 32 rows x 32 f4
      int o = e >> 5, qd = e & 31;
      f4 x = *(const f4*)(wc + (oh + o)*128 + qd*4);
      int col = qd * 4;
      float* dst = (col < 64) ? &WcL[o*65 + col] : &WvL[o*65 + col - 64];
#pragma unroll
      for (int jj = 0; jj < 4; ++jj) dst[jj] = x[jj];
    }
    for (int e = tid; e < 256; e += 256) {     // ww: 256 f4
      f4 x = *(const f4*)((const float*)ww + e*4);
#pragma unroll
      for (int jj = 0; jj < 4; ++jj) wwL[e*4 + jj] = x[jj];
    }
  } else {
    const u16* wc = (const u16*)wc33;
    for (int e = tid; e < 2048; e += 256) {
      int o = e >> 6, q2 = e & 63;
      u32 x = *(const u32*)(wc + (oh + o)*128 + q2*2);
      int col = q2 * 2;
      float v0 = bf2f((u16)(x & 0xFFFF)), v1 = bf2f((u16)(x >> 16));
      if (col < 64) { WcL[o*65 + col] = v0; WcL[o*65 + col + 1] = v1; }
      else { WvL[o*65 + col - 64] = v0; WvL[o*65 + col - 63] = v1; }
    }
    for (int e = tid; e < 512; e += 256) {
      u32 x = *(const u32*)((const u16*)ww + e*2);
      wwL[e*2]     = bf2f((u16)(x & 0xFFFF));
      wwL[e*2 + 1] = bf2f((u16)(x >> 16));
    }
  }
  if (tid < 64) bwL[tid] = cvt(bw, tid, wfl);
  if (vf) {
    const float* v = (const float*)vid;
    for (int e = tid; e < 1536; e += 256) {   // f4 loads
      int c = e / 24, qd = e % 24;
      *(f4*)&vidL[c*96 + qd*4] = *(const f4*)(v + (size_t)(b*64 + c)*HWp + y*96 + qd*4);
    }
  } else {
    const u16* v = (const u16*)vid;
    for (int e = tid; e < 3072; e += 256) {   // u32 = 2 px
      int c = e / 48, pp = (e % 48) * 2;
      u32 x = *(const u32*)(v + (size_t)(b*64 + c)*HWp + y*96 + pp);
      vidL[c*96 + pp]     = bf2f((u16)(x & 0xFFFF));
      vidL[c*96 + pp + 1] = bf2f((u16)(x >> 16));
    }
  }
  if (tid < 96) {  // matches(v) = {(qi, off): clip(4*qi + off - 3, 0, 95) == v}
    int cnt = 0;
#pragma unroll 1
    for (int qy = 0; qy < 24; ++qy)
      for (int off = 0; off < 7; ++off) {
        int p = clampi(qy*4 + off - 3, 0, 95);
        if (p == tid && cnt < 4) { MQL[tid*4 + cnt] = (u8)qy; MRL[tid*4 + cnt] = (u8)off; ++cnt; }
      }
    McL[tid] = (u8)cnt;
  }
  __syncthreads();

  // fold W1/B0 (all-LDS reads) + gather znL — same phase
  for (int e = tid; e < 512; e += 256) {
    int o = e >> 4, ci = e & 15;
    float s = 0.f;
    for (int c = 0; c < 64; ++c) s += WcL[o*65 + c] * wwL[c*16 + ci];
    W1L[o*17 + ci] = s;
  }
  if (tid < 32) {
    float s = cvt(bc33, oh + tid, wfl);
    for (int c = 0; c < 64; ++c) s += WcL[tid*65 + c] * bwL[c];
    B0L[tid] = s;
  }
  {
    const float* zG = (const float*)(ws + O_Z) + (size_t)b * 576 * 784;
    const int mcy = McL[y];
    for (int e = tid; e < 384; e += 256) {
      int x = e >> 2, cq = e & 3;
      int mcx = McL[x];
      f4 s = 0.f;
      for (int a = 0; a < mcy; ++a) {
        int qy = MQL[y*4 + a], rr = MRL[y*4 + a];
        size_t rowbase = ((size_t)qy * 24) * 784 + (size_t)(rr * 7) * 16 + cq * 4;
        for (int b2 = 0; b2 < mcx; ++b2) {
          int qx = MQL[x*4 + b2], ss = MRL[x*4 + b2];
          s += *(const f4*)(zG + rowbase + (size_t)qx * 784 + ss * 16);
        }
      }
      float invc = 1.f / (float)(mcy * mcx);
#pragma unroll
      for (int j = 0; j < 4; ++j) znL[(cq*4 + j)*96 + x] = s[j] * invc;
    }
  }
  __syncthreads();

  const int o = tid >> 3, xq = tid & 7;   // 32 o x 8 xq; 12 x per thread
  f4 a0, a1, a2;
  { float bz = B0L[o]; a0 = bz; a1 = bz; a2 = bz; }
  for (int ci = 0; ci < 16; ++ci) {
    float w = W1L[o*17 + ci];
    const f4* zp = (const f4*)&znL[ci*96 + xq*12];
    a0 += zp[0] * w; a1 += zp[1] * w; a2 += zp[2] * w;
  }
  for (int c = 0; c < 64; ++c) {
    float w = WvL[o*65 + c];
    const f4* vp = (const f4*)&vidL[c*96 + xq*12];
    a0 += vp[0] * w; a1 += vp[1] * w; a2 += vp[2] * w;
  }
  float* op = out + (size_t)(b*64 + oh + o) * HWp + y*96 + xq*12;
  *(f4*)(op + 0) = a0; *(f4*)(op + 4) = a1; *(f4*)(op + 8) = a2;
}

extern "C" void kernel_launch(void* const* d_in, const int* in_sizes, int n_in,
                              void* d_out, int out_size, void* d_ws, size_t ws_size,
                              hipStream_t stream)
{
  (void)in_sizes; (void)n_in; (void)out_size;
  const void* vid  = d_in[0];
  const void* wth  = d_in[1];
  const void* bth  = d_in[2];
  const void* wph  = d_in[3];
  const void* bph  = d_in[4];
  const void* wg   = d_in[5];
  const void* bg   = d_in[6];
  const void* ww   = d_in[7];
  const void* bw   = d_in[8];
  const void* wc33 = d_in[9];
  const void* bc33 = d_in[10];
  u8* ws = (u8*)d_ws;
  if (ws_size < WS_NEED) return;

  hipLaunchKernelGGL(k1_conv, dim3(288), dim3(256), 0, stream, vid, wth, bth, wph, bph, wg, bg, ws);
  hipLaunchKernelGGL(k2_attn, dim3(1152), dim3(256), 0, stream, ws);
  hipLaunchKernelGGL(k3_out, dim3(384), dim3(256), 0, stream, vid, ww, bw, wc33, bc33, (float*)d_out, ws);
}

// Round 13
// 156.421 us; speedup vs baseline: 4.1597x; 4.1597x over previous
//
#include <hip/hip_runtime.h>
#include <stdint.h>

typedef unsigned int u32;
typedef unsigned short u16;
typedef unsigned char u8;
typedef unsigned long long u64;
typedef _Float16 h2 __attribute__((ext_vector_type(2)));
typedef _Float16 h4 __attribute__((ext_vector_type(4)));
typedef _Float16 h8 __attribute__((ext_vector_type(8)));
typedef float f4 __attribute__((ext_vector_type(4)));

#define DEV __device__ __forceinline__

constexpr int HWp = 9216;   // 96*96

// ---------- workspace layout (bytes) ----------
constexpr size_t O_I16 = 0;                          // f16 [b][9216][48]: th 0-15, ph 16-31, g 32-47
constexpr size_t N_I16 = 2ull * 9216 * 48;           // halves
constexpr size_t O_Z   = O_I16 + N_I16 * 2;          // f32 [b][576][49][16] per-query z (normalized)
constexpr size_t N_Z   = 2ull * 576 * 784;
constexpr size_t WS_NEED = O_Z + N_Z * 4;            // ~5.38 MB

DEV float bf2f(u16 x) { return __uint_as_float(((u32)x) << 16); }
DEV int clampi(int v, int lo, int hi) { return v < lo ? lo : (v > hi ? hi : v); }
DEV float cvt(const void* p, int i, bool f32) {
  return f32 ? ((const float*)p)[i] : bf2f(((const u16*)p)[i]);
}
DEV float dot2(h2 a, h2 b, float c) {
#if __has_builtin(__builtin_amdgcn_fdot2)
  return __builtin_amdgcn_fdot2(a, b, c, false);
#else
  return c + (float)a[0]*(float)b[0] + (float)a[1]*(float)b[1];
#endif
}
DEV float dot8(h8 a, h8 b, float c) {
  c = dot2(__builtin_shufflevector(a,a,0,1), __builtin_shufflevector(b,b,0,1), c);
  c = dot2(__builtin_shufflevector(a,a,2,3), __builtin_shufflevector(b,b,2,3), c);
  c = dot2(__builtin_shufflevector(a,a,4,5), __builtin_shufflevector(b,b,4,5), c);
  c = dot2(__builtin_shufflevector(a,a,6,7), __builtin_shufflevector(b,b,6,7), c);
  return c;
}
// per-block dtype detect: sample first 256 u16 of array; f32 data -> ~28 hits, bf16 -> 0.
DEV bool hit256(const void* p, int tid) {
  u16 v = ((const u16*)p)[tid];
  return (((u32)v >> 7) & 0xFFu) >= 0xC8u;
}

// ---------- K1: conv1x1 -> channel-last f16 image [b][px][48]; self-sufficient ----------
__global__ __launch_bounds__(256, 2) void k1_conv(const void* vid, const void* wth, const void* bth,
    const void* wph, const void* bph, const void* wg, const void* bg, u8* ws)
{
  __shared__ float vidL[64 * 65];        // [px][c] pad 65
  __shared__ float wL[48 * 65];          // [o][c] pad 65
  __shared__ float bL[48];
  __shared__ __align__(16) _Float16 outL[64 * 48];
  __shared__ int redL[8];
  int tid = threadIdx.x;
  int g0 = blockIdx.x * 64;
  int b = g0 / HWp, px0 = g0 % HWp;

  {
    u64 b1 = __ballot(hit256(vid, tid));
    u64 b2 = __ballot(hit256(wth, tid));
    if ((tid & 63) == 0) { redL[tid >> 6] = __popcll(b1); redL[4 + (tid >> 6)] = __popcll(b2); }
  }
  __syncthreads();
  const bool vf = (redL[0] + redL[1] + redL[2] + redL[3]) >= 4;
  const bool wf = (redL[4] + redL[5] + redL[6] + redL[7]) >= 4;

  if (wf) {  // vectorized weight staging: 3 f4 loads/thread
    for (int e = tid; e < 768; e += 256) {
      int a = e >> 8, j = e & 255;
      int o = j >> 4, c4 = (j & 15) << 2;
      const float* src = (a == 0) ? (const float*)wth : (a == 1) ? (const float*)wph : (const float*)wg;
      f4 x = *(const f4*)(src + o*64 + c4);
#pragma unroll
      for (int jj = 0; jj < 4; ++jj) wL[(a*16 + o)*65 + c4 + jj] = x[jj];
    }
  } else {
    for (int e = tid; e < 384; e += 256) {
      int a = e >> 7, j = e & 127;
      int o = j >> 5, c2 = (j & 31) << 1;
      const u16* src = (a == 0) ? (const u16*)wth : (a == 1) ? (const u16*)wph : (const u16*)wg;
      u32 x = *(const u32*)(src + o*64 + c2);
      wL[(a*16 + o)*65 + c2]     = bf2f((u16)(x & 0xFFFF));
      wL[(a*16 + o)*65 + c2 + 1] = bf2f((u16)(x >> 16));
    }
  }
  if (tid < 48) bL[tid] = (tid < 16) ? cvt(bth, tid, wf) : (tid < 32) ? cvt(bph, tid-16, wf) : cvt(bg, tid-32, wf);
  if (vf) {
    const float* v = (const float*)vid;
    for (int e = tid; e < 1024; e += 256) {   // f4 loads: 16B/lane
      int c = e >> 4, qd = e & 15;
      f4 x = *(const f4*)(v + (size_t)(b*64 + c)*HWp + px0 + qd*4);
#pragma unroll
      for (int j = 0; j < 4; ++j) vidL[(qd*4 + j)*65 + c] = x[j];
    }
  } else {
    const u16* v = (const u16*)vid;
    for (int e = tid; e < 2048; e += 256) {   // u32 = 2 px
      int c = e >> 5, pp = (e & 31) * 2;
      u32 x = *(const u32*)(v + (size_t)(b*64 + c)*HWp + px0 + pp);
      vidL[pp*65 + c]     = bf2f((u16)(x & 0xFFFF));
      vidL[(pp+1)*65 + c] = bf2f((u16)(x >> 16));
    }
  }
  __syncthreads();

  int px = tid >> 2, h = tid & 3;
  float acc[12];
#pragma unroll
  for (int j = 0; j < 12; ++j) acc[j] = bL[h*12 + j];
  for (int c = 0; c < 64; ++c) {
    float v = vidL[px*65 + c];
#pragma unroll
    for (int j = 0; j < 12; ++j) acc[j] += wL[(h*12 + j)*65 + c] * v;
  }
#pragma unroll
  for (int j = 0; j < 12; ++j) outL[px*48 + h*12 + j] = (_Float16)acc[j];
  __syncthreads();

  _Float16* img = (_Float16*)(ws + O_I16);
  for (int e = tid; e < 384; e += 256) {   // coalesced h8 stores
    int p = e / 6, seg = e % 6;
    *(h8*)(img + (size_t)(b*HWp + px0 + p)*48 + seg*8) = *(const h8*)&outL[p*48 + seg*8];
  }
}

// ---------- K2: LDS-tiled attention; paired-candidate sliding window; radix select ----------
__global__ __launch_bounds__(256, 2) void k2_attn(u8* ws)
{
  __shared__ __align__(16) _Float16 tA[729*8], tB[729*8];  // phi(then g) ch0-7 / ch8-15 planes
  __shared__ __align__(16) _Float16 thA[49*8], thB[49*8];  // theta planes
  __shared__ float scL[441];
  __shared__ u8 crL[441], ccL[441];
  __shared__ u16 selL[100];
  __shared__ float wgtF[104];  // unnormalized weights (wave-0 scratch)
  __shared__ u32 wgtH[100];    // normalized weight as packed h2

  const int tid = threadIdx.x, blk = blockIdx.x;
  const int b = blk / 576, q = blk % 576;
  const int qi = (q / 24) * 4, qj = (q % 24) * 4;
  const _Float16* I = (const _Float16*)(ws + O_I16) + (size_t)b * HWp * 48;

  for (int e = tid; e < 441; e += 256) {
    int d1 = e / 21, d2 = e % 21;
    crL[e] = (u8)clampi(qi + d1 - 10, 0, 95);
    ccL[e] = (u8)clampi(qj + d2 - 10, 0, 95);
  }
  for (int e = tid; e < 98; e += 256) {   // theta patch
    int p = e >> 1, hf = e & 1, di = p / 7, dj = p % 7;
    int ty = clampi(qi + di - 3, 0, 95), tx = clampi(qj + dj - 3, 0, 95);
    *(h8*)&(hf ? thB : thA)[p*8] = *(const h8*)(I + (size_t)(ty*96 + tx)*48 + hf*8);
  }
  for (int e = tid; e < 1458; e += 256) { // phi tile: row t holds image row clip(qi-13+t)
    int p = e >> 1, hf = e & 1, row = p / 27, col = p % 27;
    int gy = clampi(qi - 13 + row, 0, 95), gx = clampi(qj - 13 + col, 0, 95);
    *(h8*)&(hf ? tB : tA)[p*8] = *(const h8*)(I + (size_t)(gy*96 + gx)*48 + 16 + hf*8);
  }
  __syncthreads();

  { // scores: paired candidates (c0=row*21+2m, c1=c0+1) share an 8-wide column window.
    // w_j = clip(cc0 + j - 3); s = cc1 - cc0 in {0,1}; c1's col map = w_{dj+s} (exact by
    // monotone 1-Lipschitz clip). Accumulation order per candidate identical to R10
    // (dj ascending) => bit-identical scores.
    int u = tid;
    bool active = u < 231;
    int uu = active ? u : 0;
    int row = uu / 11, m = uu % 11;
    bool has1 = active && (m < 10);
    int d2_0 = (m < 10) ? 2*m : 20;
    int c0 = row*21 + d2_0;
    int cc0 = clampi(qj + d2_0 - 10, 0, 95);
    int s = clampi(qj + d2_0 - 9, 0, 95) - cc0;   // 0 or 1
    int cr0 = clampi(qi + row - 10, 0, 95);
    int ro[7], tw[8];
#pragma unroll
    for (int i = 0; i < 7; ++i) ro[i] = (clampi(cr0 + i - 3, 0, 95) - qi + 13) * 216;  // *27*8
#pragma unroll
    for (int j = 0; j < 8; ++j) {
      int t = clampi(cc0 + j - 3, 0, 95) - (qj - 13);
      tw[j] = (t > 26 ? 26 : t) * 8;
    }
    float a0A = 0.f, a0B = 0.f, a1A = 0.f, a1B = 0.f;
    for (int di = 0; di < 7; ++di) {
      int r = ro[di];
#pragma unroll
      for (int j = 0; j < 8; ++j) {
        h8 hA = *(const h8*)&tA[r + tw[j]];
        h8 hB = *(const h8*)&tB[r + tw[j]];
        if (j < 7) {
          int p0 = (di*7 + j)*8;
          a0A = dot8(*(const h8*)&thA[p0], hA, a0A);
          a0B = dot8(*(const h8*)&thB[p0], hB, a0B);
        }
        {
          int dj1 = j - s;
          bool v1 = has1 && (dj1 >= 0) && (dj1 <= 6);
          int p1 = (di*7 + clampi(dj1, 0, 6))*8;
          float rA = dot8(*(const h8*)&thA[p1], hA, a1A);
          float rB = dot8(*(const h8*)&thB[p1], hB, a1B);
          a1A = v1 ? rA : a1A;
          a1B = v1 ? rB : a1B;
        }
      }
    }
    if (active) scL[c0] = a0A + a0B;
    if (has1) scL[c0 + 1] = a1A + a1B;
  }
  __syncthreads();

  if (tid >= 64) {  // waves 1-3: restage tiles with g while wave 0 selects
    for (int e = tid - 64; e < 1458; e += 192) {
      int p = e >> 1, hf = e & 1, row = p / 27, col = p % 27;
      int gy = clampi(qi - 13 + row, 0, 95), gx = clampi(qj - 13 + col, 0, 95);
      *(h8*)&(hf ? tB : tA)[p*8] = *(const h8*)(I + (size_t)(gy*96 + gx)*48 + 32 + hf*8);
    }
  } else {
    // wave 0: exact top-100 via 41-round radix threshold on UNIQUE keys
    // key = (orderable_score << 9) | (511 - idx): distinct, desc order = score desc then idx asc (jax stable)
    const int lane = tid;
    const u64 lt = (1ull << lane) - 1ull;
    u64 kv[7];
#pragma unroll
    for (int s = 0; s < 7; ++s) {
      int idx = s * 64 + lane;
      if (idx < 441) {
        u32 bb = __float_as_uint(scL[idx]);
        u32 ob = (bb & 0x80000000u) ? ~bb : (bb | 0x80000000u);
        kv[s] = ((u64)ob << 9) | (u64)(511 - idx);
      } else kv[s] = 0ull;
    }
    u64 mx = kv[0];
#pragma unroll
    for (int s = 1; s < 7; ++s) mx = (kv[s] > mx) ? kv[s] : mx;
    for (int off = 1; off < 64; off <<= 1) { u64 o = __shfl_xor(mx, off, 64); mx = (o > mx) ? o : mx; }
    float vmax;
    { u32 ob = (u32)(mx >> 9); u32 bb = (ob & 0x80000000u) ? (ob & 0x7FFFFFFFu) : ~ob; vmax = __uint_as_float(bb); }
    u64 T = 0;
    for (int bit = 40; bit >= 0; --bit) {
      u64 cand = T | (1ull << bit);
      int cnt = 0;
#pragma unroll
      for (int s = 0; s < 7; ++s) cnt += __popcll(__ballot(kv[s] >= cand));
      if (cnt >= 100) T = cand;
    }
    // T is exactly the 100th-largest key; kv >= T selects exactly 100 (keys unique)
    float dloc = 0.f; int base = 0;
#pragma unroll
    for (int s = 0; s < 7; ++s) {
      bool incl = kv[s] >= T;
      u64 ib = __ballot(incl);
      if (incl) {
        int idx = 511 - (int)(kv[s] & 0x1FFull);
        u32 ob = (u32)(kv[s] >> 9);
        u32 bb = (ob & 0x80000000u) ? (ob & 0x7FFFFFFFu) : ~ob;
        float w = __expf(10.f * (__uint_as_float(bb) - vmax));
        int pos = base + __popcll(ib & lt);
        selL[pos] = (u16)idx;
        wgtF[pos] = w;
        dloc += w;
      }
      base += __popcll(ib);
    }
    for (int off = 1; off < 64; off <<= 1) dloc += __shfl_xor(dloc, off, 64);
    float inv = 1.f / dloc;
    for (int k = lane; k < 100; k += 64) {
      _Float16 wh = (_Float16)(wgtF[k] * inv);
      h2 p2; p2[0] = wh; p2[1] = wh;
      wgtH[k] = __builtin_bit_cast(u32, p2);
    }
  }
  __syncthreads();

  // z: thread = (pixel p, channel-quad cq); packed f16 accumulation; coalesced f4 store
  if (tid < 196) {
    int p = tid >> 2, cq = tid & 3;
    int di = p / 7, dj = p % 7;
    const _Float16* base = (cq < 2 ? tA : tB) + (cq & 1) * 4;
    h2 accA; accA[0] = (_Float16)0.f; accA[1] = (_Float16)0.f;
    h2 accB = accA;
    for (int k = 0; k < 100; ++k) {
      int si = selL[k];
      int ty = clampi((int)crL[si] + di - 3, 0, 95) - qi + 13;
      int tx = clampi((int)ccL[si] + dj - 3, 0, 95) - qj + 13;
      h4 g = *(const h4*)&base[(ty*27 + tx)*8];
      h2 w2 = __builtin_bit_cast(h2, wgtH[k]);
      accA += w2 * __builtin_shufflevector(g, g, 0, 1);
      accB += w2 * __builtin_shufflevector(g, g, 2, 3);
    }
    f4 zv; zv[0] = (float)accA[0]; zv[1] = (float)accA[1]; zv[2] = (float)accB[0]; zv[3] = (float)accB[1];
    *(f4*)((float*)(ws + O_Z) + (size_t)(b*576 + q)*784 + tid*4) = zv;   // p*16 + cq*4 == tid*4
  }
}

// ---------- K3: self-sufficient gather overlap-add + folded epilogue ----------
__global__ __launch_bounds__(256, 2) void k3_out(const void* vid, const void* ww, const void* bw,
    const void* wc33, const void* bc33, float* out, const u8* ws)
{
  __shared__ float znL[16 * 96];
  __shared__ float vidL[64 * 96];
  __shared__ float WvL[32 * 65];
  __shared__ float WcL[32 * 65];
  __shared__ float wwL[1024];
  __shared__ float bwL[64];
  __shared__ float W1L[32 * 17];
  __shared__ float B0L[32];
  __shared__ u8 McL[96], MQL[384], MRL[384];
  __shared__ int redL[8];
  const int tid = threadIdx.x, blk = blockIdx.x;
  const int b = blk / 192, rem = blk % 192, y = rem >> 1, oh = (rem & 1) * 32;

  {
    u64 b1 = __ballot(hit256(vid, tid));
    u64 b2 = __ballot(hit256(wc33, tid));
    if ((tid & 63) == 0) { redL[tid >> 6] = __popcll(b1); redL[4 + (tid >> 6)] = __popcll(b2); }
  }
  __syncthreads();
  const bool vf = (redL[0] + redL[1] + redL[2] + redL[3]) >= 4;
  const bool wfl = (redL[4] + redL[5] + redL[6] + redL[7]) >= 4;

  if (wfl) {   // vectorized weight staging
    const float* wc = (const float*)wc33;
    for (int e = tid; e < 1024; e += 256) {    // 32 rows x 32 f4
      int o = e >> 5, qd = e & 31;
      f4 x = *(const f4*)(wc + (oh + o)*128 + qd*4);
      int col = qd * 4;
      float* dst = (col < 64) ? &WcL[o*65 + col] : &WvL[o*65 + col - 64];
#pragma unroll
      for (int jj = 0; jj < 4; ++jj) dst[jj] = x[jj];
    }
    for (int e = tid; e < 256; e += 256) {     // ww: 256 f4
      f4 x = *(const f4*)((const float*)ww + e*4);
#pragma unroll
      for (int jj = 0; jj < 4; ++jj) wwL[e*4 + jj] = x[jj];
    }
  } else {
    const u16* wc = (const u16*)wc33;
    for (int e = tid; e < 2048; e += 256) {
      int o = e >> 6, q2 = e & 63;
      u32 x = *(const u32*)(wc + (oh + o)*128 + q2*2);
      int col = q2 * 2;
      float v0 = bf2f((u16)(x & 0xFFFF)), v1 = bf2f((u16)(x >> 16));
      if (col < 64) { WcL[o*65 + col] = v0; WcL[o*65 + col + 1] = v1; }
      else { WvL[o*65 + col - 64] = v0; WvL[o*65 + col - 63] = v1; }
    }
    for (int e = tid; e < 512; e += 256) {
      u32 x = *(const u32*)((const u16*)ww + e*2);
      wwL[e*2]     = bf2f((u16)(x & 0xFFFF));
      wwL[e*2 + 1] = bf2f((u16)(x >> 16));
    }
  }
  if (tid < 64) bwL[tid] = cvt(bw, tid, wfl);
  if (vf) {
    const float* v = (const float*)vid;
    for (int e = tid; e < 1536; e += 256) {   // f4 loads
      int c = e / 24, qd = e % 24;
      *(f4*)&vidL[c*96 + qd*4] = *(const f4*)(v + (size_t)(b*64 + c)*HWp + y*96 + qd*4);
    }
  } else {
    const u16* v = (const u16*)vid;
    for (int e = tid; e < 3072; e += 256) {   // u32 = 2 px
      int c = e / 48, pp = (e % 48) * 2;
      u32 x = *(const u32*)(v + (size_t)(b*64 + c)*HWp + y*96 + pp);
      vidL[c*96 + pp]     = bf2f((u16)(x & 0xFFFF));
      vidL[c*96 + pp + 1] = bf2f((u16)(x >> 16));
    }
  }
  if (tid < 96) {  // matches(v) = {(qi, off): clip(4*qi + off - 3, 0, 95) == v}
    int cnt = 0;
#pragma unroll 1
    for (int qy = 0; qy < 24; ++qy)
      for (int off = 0; off < 7; ++off) {
        int p = clampi(qy*4 + off - 3, 0, 95);
        if (p == tid && cnt < 4) { MQL[tid*4 + cnt] = (u8)qy; MRL[tid*4 + cnt] = (u8)off; ++cnt; }
      }
    McL[tid] = (u8)cnt;
  }
  __syncthreads();

  // fold W1/B0 (all-LDS reads) + gather znL — same phase
  for (int e = tid; e < 512; e += 256) {
    int o = e >> 4, ci = e & 15;
    float s = 0.f;
    for (int c = 0; c < 64; ++c) s += WcL[o*65 + c] * wwL[c*16 + ci];
    W1L[o*17 + ci] = s;
  }
  if (tid < 32) {
    float s = cvt(bc33, oh + tid, wfl);
    for (int c = 0; c < 64; ++c) s += WcL[tid*65 + c] * bwL[c];
    B0L[tid] = s;
  }
  {
    const float* zG = (const float*)(ws + O_Z) + (size_t)b * 576 * 784;
    const int mcy = McL[y];
    for (int e = tid; e < 384; e += 256) {
      int x = e >> 2, cq = e & 3;
      int mcx = McL[x];
      f4 s = 0.f;
      for (int a = 0; a < mcy; ++a) {
        int qy = MQL[y*4 + a], rr = MRL[y*4 + a];
        size_t rowbase = ((size_t)qy * 24) * 784 + (size_t)(rr * 7) * 16 + cq * 4;
        for (int b2 = 0; b2 < mcx; ++b2) {
          int qx = MQL[x*4 + b2], ss = MRL[x*4 + b2];
          s += *(const f4*)(zG + rowbase + (size_t)qx * 784 + ss * 16);
        }
      }
      float invc = 1.f / (float)(mcy * mcx);
#pragma unroll
      for (int j = 0; j < 4; ++j) znL[(cq*4 + j)*96 + x] = s[j] * invc;
    }
  }
  __syncthreads();

  const int o = tid >> 3, xq = tid & 7;   // 32 o x 8 xq; 12 x per thread
  f4 a0, a1, a2;
  { float bz = B0L[o]; a0 = bz; a1 = bz; a2 = bz; }
  for (int ci = 0; ci < 16; ++ci) {
    float w = W1L[o*17 + ci];
    const f4* zp = (const f4*)&znL[ci*96 + xq*12];
    a0 += zp[0] * w; a1 += zp[1] * w; a2 += zp[2] * w;
  }
  for (int c = 0; c < 64; ++c) {
    float w = WvL[o*65 + c];
    const f4* vp = (const f4*)&vidL[c*96 + xq*12];
    a0 += vp[0] * w; a1 += vp[1] * w; a2 += vp[2] * w;
  }
  float* op = out + (size_t)(b*64 + oh + o) * HWp + y*96 + xq*12;
  *(f4*)(op + 0) = a0; *(f4*)(op + 4) = a1; *(f4*)(op + 8) = a2;
}

extern "C" void kernel_launch(void* const* d_in, const int* in_sizes, int n_in,
                              void* d_out, int out_size, void* d_ws, size_t ws_size,
                              hipStream_t stream)
{
  (void)in_sizes; (void)n_in; (void)out_size;
  const void* vid  = d_in[0];
  const void* wth  = d_in[1];
  const void* bth  = d_in[2];
  const void* wph  = d_in[3];
  const void* bph  = d_in[4];
  const void* wg   = d_in[5];
  const void* bg   = d_in[6];
  const void* ww   = d_in[7];
  const void* bw   = d_in[8];
  const void* wc33 = d_in[9];
  const void* bc33 = d_in[10];
  u8* ws = (u8*)d_ws;
  if (ws_size < WS_NEED) return;

  hipLaunchKernelGGL(k1_conv, dim3(288), dim3(256), 0, stream, vid, wth, bth, wph, bph, wg, bg, ws);
  hipLaunchKernelGGL(k2_attn, dim3(1152), dim3(256), 0, stream, ws);
  hipLaunchKernelGGL(k3_out, dim3(384), dim3(256), 0, stream, vid, ww, bw, wc33, bc33, (float*)d_out, ws);
}